// Round 8
// baseline (187.842 us; speedup 1.0000x reference)
//
#include <hip/hip_runtime.h>
#include <hip/hip_bf16.h>

#define B_  2
#define S_  2048
#define D_  1024
#define H_  16
#define HD_ 64

typedef __attribute__((ext_vector_type(8))) short bf16x8;
typedef __attribute__((ext_vector_type(4))) short bf16x4;
typedef __attribute__((ext_vector_type(4))) float f32x4;

typedef __attribute__((address_space(1))) const short gbl_short;
typedef __attribute__((address_space(3))) short lds_short;

__device__ __forceinline__ short f2bf(float f) {
  union { float f; unsigned u; } v; v.f = f;
  unsigned r = (v.u + 0x7FFFu + ((v.u >> 16) & 1u)) >> 16;
  return (short)r;
}

__device__ __forceinline__ short bf16s(float f) {
  __hip_bfloat16 h = __float2bfloat16(f);
  return *reinterpret_cast<short*>(&h);
}

// packed f32x2 -> bf16x2 (RNE), no builtin on gfx950 (T12 recipe)
__device__ __forceinline__ unsigned cvtpk(float lo, float hi) {
  unsigned r;
  asm("v_cvt_pk_bf16_f32 %0, %1, %2" : "=v"(r) : "v"(lo), "v"(hi));
  return r;
}

// ---------------- merged prep: weight transpose+cast (z=0..3) | x cast (z=4..7) ----------------
__global__ __launch_bounds__(256) void prep_kernel(
    const float* __restrict__ x,
    const float* __restrict__ w0, const float* __restrict__ w1,
    const float* __restrict__ w2, const float* __restrict__ w3,
    short* __restrict__ xb,
    short* __restrict__ t0, short* __restrict__ t1,
    short* __restrict__ t2, short* __restrict__ t3) {
  const int z = blockIdx.z;
  if (z < 4) {
    const float* W = z == 0 ? w0 : z == 1 ? w1 : z == 2 ? w2 : w3;
    short* T       = z == 0 ? t0 : z == 1 ? t1 : z == 2 ? t2 : t3;
    __shared__ float tile[32][33];
    int tx = threadIdx.x, ty = threadIdx.y;
    int x0 = blockIdx.x * 32, y0 = blockIdx.y * 32;
#pragma unroll
    for (int i = 0; i < 4; ++i)
      tile[ty + i * 8][tx] = W[(y0 + ty + i * 8) * D_ + x0 + tx];
    __syncthreads();
#pragma unroll
    for (int i = 0; i < 4; ++i)
      T[(x0 + ty + i * 8) * D_ + y0 + tx] = f2bf(tile[tx][ty + i * 8]);
  } else {
    // cast 4M floats as 1M float4 across 4096 virtual blocks (z=4..7 x 32 x 32)
    int bid = (z - 4) * 1024 + blockIdx.y * 32 + blockIdx.x;
    int i = bid * 256 + threadIdx.y * 32 + threadIdx.x;
    float4 v = ((const float4*)x)[i];
    short4 o;
    o.x = f2bf(v.x); o.y = f2bf(v.y); o.z = f2bf(v.z); o.w = f2bf(v.w);
    ((short4*)xb)[i] = o;
  }
}

// ---------------- QKV GEMM: 128x128, BK=32, 3-buffer counted-vmcnt pipeline ----------------
// 1-D grid with XCD swizzle (T1): id%8 = n-panel -> each XCD owns one weight
// N-panel per matrix (256 KB, L2-resident) instead of all 8 XCDs refetching
// every panel.  which = id>>8 (Q/K/V), m = (id&255)>>3, n = id&7.
__global__ __launch_bounds__(256) void qkv_gemm(
    const short* __restrict__ xb,
    const short* __restrict__ Wqt, const short* __restrict__ Wkt, const short* __restrict__ Wvt,
    const float* __restrict__ bq, const float* __restrict__ bk, const float* __restrict__ bv,
    short* __restrict__ Qb, short* __restrict__ Kb, short* __restrict__ Vtb) {
  const int id = blockIdx.x;
  const int which = id >> 8;                       // 0..2
  const int rr = id & 255;
  const int m0 = (rr >> 3) * 128;                  // 32 m-tiles
  const int n0 = (rr & 7) * 128;                   // 8 n-tiles, pinned per XCD
  const short* Bt   = which == 0 ? Wqt : which == 1 ? Wkt : Wvt;
  const float* bias = which == 0 ? bq  : which == 1 ? bk  : bv;
  const float scl   = which == 0 ? 0.125f * 1.44269504089f : 1.0f;
  const int lane = threadIdx.x & 63, wave = threadIdx.x >> 6;
  const int l15 = lane & 15, quad = lane >> 4;
  const int wm = wave & 1, wn = wave >> 1;
  const int srow = lane >> 2;
  const int skp  = (((lane & 3) ^ ((srow >> 1) & 3)) * 8);
  const int rsw  = (l15 >> 1) & 3;

  __shared__ short lA[3][128 * 32];
  __shared__ short lB[3][128 * 32];

  f32x4 acc[4][4];
#pragma unroll
  for (int mi = 0; mi < 4; ++mi)
#pragma unroll
    for (int ni = 0; ni < 4; ++ni) { f32x4 z = {0.f, 0.f, 0.f, 0.f}; acc[mi][ni] = z; }

  auto stage = [&](int it, int buf) {
    int kk = it * 32;
#pragma unroll
    for (int j = 0; j < 2; ++j) {
      int c = wave * 2 + j;
      int row = c * 16 + srow;
      __builtin_amdgcn_global_load_lds(
          (gbl_short*)(xb + (m0 + row) * D_ + kk + skp),
          (lds_short*)(&lA[buf][0] + c * 512 + lane * 8), 16, 0, 0);
      __builtin_amdgcn_global_load_lds(
          (gbl_short*)(Bt + (n0 + row) * D_ + kk + skp),
          (lds_short*)(&lB[buf][0] + c * 512 + lane * 8), 16, 0, 0);
    }
  };

  auto compute = [&](int cur) {
    bf16x8 af[4], bf[4];
#pragma unroll
    for (int i = 0; i < 4; ++i) {
      af[i] = *(const bf16x8*)(&lA[cur][0] + (wm * 64 + i * 16 + l15) * 32 + ((quad ^ rsw)) * 8);
      bf[i] = *(const bf16x8*)(&lB[cur][0] + (wn * 64 + i * 16 + l15) * 32 + ((quad ^ rsw)) * 8);
    }
#pragma unroll
    for (int mi = 0; mi < 4; ++mi)
#pragma unroll
      for (int ni = 0; ni < 4; ++ni)
        acc[mi][ni] = __builtin_amdgcn_mfma_f32_16x16x32_bf16(af[mi], bf[ni], acc[mi][ni], 0, 0, 0);
  };

  stage(0, 0);
  stage(1, 1);
  for (int it = 0; it < 30; ++it) {
    stage(it + 2, (it + 2) % 3);
    asm volatile("s_waitcnt vmcnt(8)" ::: "memory");
    __builtin_amdgcn_s_barrier();
    compute(it % 3);
    asm volatile("" ::: "memory");
    __builtin_amdgcn_s_barrier();
  }
  asm volatile("s_waitcnt vmcnt(4)" ::: "memory");
  __builtin_amdgcn_s_barrier();
  compute(0);
  asm volatile("s_waitcnt vmcnt(0)" ::: "memory");
  __builtin_amdgcn_s_barrier();
  compute(1);

#pragma unroll
  for (int mi = 0; mi < 4; ++mi) {
    int m = m0 + wm * 64 + mi * 16 + quad * 4;
    int bb = m >> 11;
    int s0 = m & (S_ - 1);
#pragma unroll
    for (int ni = 0; ni < 4; ++ni) {
      int n = n0 + wn * 64 + ni * 16 + l15;
      int h = n >> 6, hd = n & 63;
      float bsv = bias[n];
      if (which < 2) {
        short* dst = which == 0 ? Qb : Kb;
#pragma unroll
        for (int r = 0; r < 4; ++r)
          dst[((bb * H_ + h) * S_ + (s0 + r)) * HD_ + hd] = f2bf((acc[mi][ni][r] + bsv) * scl);
      } else {
        short4 pk;
        pk.x = f2bf(acc[mi][ni][0] + bsv);
        pk.y = f2bf(acc[mi][ni][1] + bsv);
        pk.z = f2bf(acc[mi][ni][2] + bsv);
        pk.w = f2bf(acc[mi][ni][3] + bsv);
        *(short4*)(Vtb + ((bb * H_ + h) * HD_ + hd) * S_ + s0) = pk;
      }
    }
  }
}

// ---------------- output projection: 128x128, same pipeline, XCD-swizzled 1-D grid ----------------
__global__ __launch_bounds__(256) void out_gemm(
    const short* __restrict__ Ob, const short* __restrict__ Wot,
    const float* __restrict__ bo, float* __restrict__ out) {
  const int id = blockIdx.x;
  const int m0 = (id >> 3) * 128;                  // 32 m-tiles
  const int n0 = (id & 7) * 128;                   // 8 n-tiles, pinned per XCD
  const int lane = threadIdx.x & 63, wave = threadIdx.x >> 6;
  const int l15 = lane & 15, quad = lane >> 4;
  const int wm = wave & 1, wn = wave >> 1;
  const int srow = lane >> 2;
  const int skp  = (((lane & 3) ^ ((srow >> 1) & 3)) * 8);
  const int rsw  = (l15 >> 1) & 3;

  __shared__ short lA[3][128 * 32];
  __shared__ short lB[3][128 * 32];

  f32x4 acc[4][4];
#pragma unroll
  for (int mi = 0; mi < 4; ++mi)
#pragma unroll
    for (int ni = 0; ni < 4; ++ni) { f32x4 z = {0.f, 0.f, 0.f, 0.f}; acc[mi][ni] = z; }

  auto stage = [&](int it, int buf) {
    int kk = it * 32;
#pragma unroll
    for (int j = 0; j < 2; ++j) {
      int c = wave * 2 + j;
      int row = c * 16 + srow;
      __builtin_amdgcn_global_load_lds(
          (gbl_short*)(Ob + (m0 + row) * D_ + kk + skp),
          (lds_short*)(&lA[buf][0] + c * 512 + lane * 8), 16, 0, 0);
      __builtin_amdgcn_global_load_lds(
          (gbl_short*)(Wot + (n0 + row) * D_ + kk + skp),
          (lds_short*)(&lB[buf][0] + c * 512 + lane * 8), 16, 0, 0);
    }
  };

  auto compute = [&](int cur) {
    bf16x8 af[4], bf[4];
#pragma unroll
    for (int i = 0; i < 4; ++i) {
      af[i] = *(const bf16x8*)(&lA[cur][0] + (wm * 64 + i * 16 + l15) * 32 + ((quad ^ rsw)) * 8);
      bf[i] = *(const bf16x8*)(&lB[cur][0] + (wn * 64 + i * 16 + l15) * 32 + ((quad ^ rsw)) * 8);
    }
#pragma unroll
    for (int mi = 0; mi < 4; ++mi)
#pragma unroll
      for (int ni = 0; ni < 4; ++ni)
        acc[mi][ni] = __builtin_amdgcn_mfma_f32_16x16x32_bf16(af[mi], bf[ni], acc[mi][ni], 0, 0, 0);
  };

  stage(0, 0);
  stage(1, 1);
  for (int it = 0; it < 30; ++it) {
    stage(it + 2, (it + 2) % 3);
    asm volatile("s_waitcnt vmcnt(8)" ::: "memory");
    __builtin_amdgcn_s_barrier();
    compute(it % 3);
    asm volatile("" ::: "memory");
    __builtin_amdgcn_s_barrier();
  }
  asm volatile("s_waitcnt vmcnt(4)" ::: "memory");
  __builtin_amdgcn_s_barrier();
  compute(0);
  asm volatile("s_waitcnt vmcnt(0)" ::: "memory");
  __builtin_amdgcn_s_barrier();
  compute(1);

#pragma unroll
  for (int mi = 0; mi < 4; ++mi) {
    int m = m0 + wm * 64 + mi * 16 + quad * 4;
#pragma unroll
    for (int ni = 0; ni < 4; ++ni) {
      int n = n0 + wn * 64 + ni * 16 + l15;
      float bsv = bo[n];
#pragma unroll
      for (int r = 0; r < 4; ++r)
        out[(m + r) * D_ + n] = acc[mi][ni][r] + bsv;
    }
  }
}

// ---------------- Flash attention v12 (verbatim round-6 passing source) ----------------
// 4 LDS buffers, stage 2 tiles -> vmcnt(8) -> barrier -> compute(t),
// compute(t+1) -> barrier.  cvt_pk softmax pack.  XCD pair-swizzle + setprio +
// S^T register-P trick.  v13's zero-C refactor REVERTED (failed refcheck at
// 1.1e-2, mechanism unexplained -> dropped per rigor discipline).
__global__ __launch_bounds__(256, 2) void attn_kernel(
    const short* __restrict__ Qb, const short* __restrict__ Kb,
    const short* __restrict__ Vtb, short* __restrict__ Ob) {
  // XCD-aware decode: id = xcd + 8*(s*16 + qt), pair = xcd*4 + s
  const int id = blockIdx.x;
  const int xcd = id & 7;
  const int slot = id >> 3;                        // 0..63
  const int pr = xcd * 4 + (slot >> 4);            // 0..31
  const int qt = slot & 15;
  const int h = pr & 15, b = pr >> 4;
  const int base = (b * H_ + h) * S_ * HD_;
  const int tid = threadIdx.x;
  const int lane = tid & 63, wave = tid >> 6;      // 0..3
  const int grp = wave >> 1;                       // key-half
  const int wq  = wave & 1;                        // q-subtile (64 q)
  const int l15 = lane & 15, quad = lane >> 4;

  __shared__ __align__(16) char smem[65536];
  short* lK = (short*)smem;                        // [4 buf][2 grp][32key*64hd]
  short* lV = (short*)(smem + 32768);              // [4 buf][2 grp][64hd*32key]

  const int q0 = qt * 128 + wq * 64;

  bf16x8 qf[4][2];
#pragma unroll
  for (int mi = 0; mi < 4; ++mi)
#pragma unroll
    for (int ks = 0; ks < 2; ++ks)
      qf[mi][ks] = *(const bf16x8*)(Qb + base + (q0 + mi * 16 + l15) * HD_ + ks * 32 + quad * 8);

  f32x4 oacc[4][4];
  f32x4 lacc[4];
#pragma unroll
  for (int mi = 0; mi < 4; ++mi) {
    f32x4 z = {0.f, 0.f, 0.f, 0.f};
    lacc[mi] = z;
#pragma unroll
    for (int nb = 0; nb < 4; ++nb) oacc[mi][nb] = z;
  }

  bf16x8 onesf;
#pragma unroll
  for (int i = 0; i < 8; ++i) onesf[i] = (short)0x3F80;   // bf16 1.0

  const int tig = tid & 127;
  const int slotK = tig & 7,  rowK = tig >> 3;     // K: 16 rows x 8 slots (+j*16)
  const int slotV = tig & 3,  rowV = tig >> 2;     // V: 32 rows x 4 slots (+j*32)
  const short* kp = Kb + base + (grp * 1024 + rowK) * HD_ + ((slotK ^ (rowK & 7)) * 8);
  const short* vp = Vtb + base + rowV * S_ + grp * 1024 + ((slotV ^ ((rowV >> 2) & 3)) * 8);
  lds_short* ldk = (lds_short*)(lK + grp * 2048 + tig * 8);
  lds_short* ldv = (lds_short*)(lV + grp * 2048 + tig * 8);

  auto stage = [&](int kt, int buf) {
#pragma unroll
    for (int j = 0; j < 2; ++j) {
      __builtin_amdgcn_global_load_lds((gbl_short*)(kp + kt * 32 * HD_ + j * 16 * HD_),
                                       ldk + buf * 4096 + j * 1024, 16, 0, 0);
      __builtin_amdgcn_global_load_lds((gbl_short*)(vp + kt * 32 + j * 32 * S_),
                                       ldv + buf * 4096 + j * 1024, 16, 0, 0);
    }
  };

  const int swzK = l15 & 7;                        // K 16B-group XOR key
  const int fsw  = (l15 >> 2) & 3;                 // V 16B-group XOR key
  const int g1 = (quad >> 1) ^ fsw;                // V physical group, keys quad*4+0..3
  const int g2 = (2 | (quad >> 1)) ^ fsw;          // V physical group, keys 16+quad*4+0..3
  const int vsub = (quad & 1) * 4;                 // 8B half within 16B group

  auto compute = [&](int buf) {
    const short* lKc = lK + buf * 4096 + grp * 2048;
    const short* lVc = lV + buf * 4096 + grp * 2048;

    // S^T = K Q^T : sacc[mi][nb], rows=keys nb*16+quad*4+r, cols=q=mi*16+l15
    f32x4 sacc[4][2];
#pragma unroll
    for (int mi = 0; mi < 4; ++mi)
#pragma unroll
      for (int nb = 0; nb < 2; ++nb) { f32x4 z = {0.f, 0.f, 0.f, 0.f}; sacc[mi][nb] = z; }
    __builtin_amdgcn_s_setprio(1);
#pragma unroll
    for (int nb = 0; nb < 2; ++nb)
#pragma unroll
      for (int ks = 0; ks < 2; ++ks) {
        bf16x8 kf = *(const bf16x8*)(lKc + (nb * 16 + l15) * 64 + (((ks * 4 + quad) ^ swzK) * 8));
#pragma unroll
        for (int mi = 0; mi < 4; ++mi)
          sacc[mi][nb] = __builtin_amdgcn_mfma_f32_16x16x32_bf16(kf, qf[mi][ks], sacc[mi][nb], 0, 0, 0);
      }
    __builtin_amdgcn_s_setprio(0);

    // P A-fragments in registers via exp2 + packed cvt
    bf16x8 af[4];
#pragma unroll
    for (int mi = 0; mi < 4; ++mi) {
      union { bf16x8 v; unsigned u[4]; } aw;
#pragma unroll
      for (int p = 0; p < 4; ++p)
        aw.u[p] = cvtpk(__builtin_amdgcn_exp2f(sacc[mi][p >> 1][(p & 1) * 2]),
                        __builtin_amdgcn_exp2f(sacc[mi][p >> 1][(p & 1) * 2 + 1]));
      af[mi] = aw.v;
    }

    // O += P V (same sigma on V's k): vf = two b64 runs per nbh
    __builtin_amdgcn_s_setprio(1);
#pragma unroll
    for (int nbh = 0; nbh < 4; ++nbh) {
      const short* vrow = lVc + (nbh * 16 + l15) * 32 + vsub;
      bf16x4 v1 = *(const bf16x4*)(vrow + g1 * 8);
      bf16x4 v2 = *(const bf16x4*)(vrow + g2 * 8);
      bf16x8 vf = __builtin_shufflevector(v1, v2, 0, 1, 2, 3, 4, 5, 6, 7);
#pragma unroll
      for (int mi = 0; mi < 4; ++mi)
        oacc[mi][nbh] = __builtin_amdgcn_mfma_f32_16x16x32_bf16(af[mi], vf, oacc[mi][nbh], 0, 0, 0);
    }
#pragma unroll
    for (int mi = 0; mi < 4; ++mi)
      lacc[mi] = __builtin_amdgcn_mfma_f32_16x16x32_bf16(af[mi], onesf, lacc[mi], 0, 0, 0);
    __builtin_amdgcn_s_setprio(0);
  };

  // drain Q-fragment loads so loop vmcnt counting is exact
  asm volatile("s_waitcnt vmcnt(0)" ::: "memory");
  stage(0, 0);
  stage(1, 1);

  for (int t = 0; t < 32; t += 2) {
    if (t < 30) {
      stage(t + 2, (t + 2) & 3);
      stage(t + 3, (t + 3) & 3);
      asm volatile("s_waitcnt vmcnt(8)" ::: "memory");
    } else {
      asm volatile("s_waitcnt vmcnt(0)" ::: "memory");
    }
    __builtin_amdgcn_s_barrier();
    compute(t & 3);
    compute((t + 1) & 3);
    asm volatile("" ::: "memory");
    __builtin_amdgcn_s_barrier();
  }

  // merge the two key-halves through LDS, normalize + write
  float* exch = (float*)smem;                      // 2 wq x 64q x 64hd f32 = 32 KB
  float* lex  = (float*)(smem + 32768);            // 128 floats (lV region, done)
  if (grp == 1) {
#pragma unroll
    for (int mi = 0; mi < 4; ++mi)
#pragma unroll
      for (int nbh = 0; nbh < 4; ++nbh)
#pragma unroll
        for (int r = 0; r < 4; ++r)
          exch[wq * 4096 + (mi * 16 + quad * 4 + r) * 64 + nbh * 16 + l15] = oacc[mi][nbh][r];
    if (l15 == 0) {
#pragma unroll
      for (int mi = 0; mi < 4; ++mi)
#pragma unroll
        for (int r = 0; r < 4; ++r)
          lex[wq * 64 + mi * 16 + quad * 4 + r] = lacc[mi][r];
    }
  }
  __syncthreads();
  if (grp == 0) {
#pragma unroll
    for (int mi = 0; mi < 4; ++mi)
#pragma unroll
      for (int r = 0; r < 4; ++r) {
        int row = mi * 16 + quad * 4 + r;
        float l2 = lex[wq * 64 + row];
        float inv = 1.0f / (lacc[mi][r] + l2);
        int sg = q0 + row;
#pragma unroll
        for (int nbh = 0; nbh < 4; ++nbh) {
          float o2 = exch[wq * 4096 + row * 64 + nbh * 16 + l15];
          Ob[(b * S_ + sg) * D_ + h * HD_ + nbh * 16 + l15] =
              bf16s((oacc[mi][nbh][r] + o2) * inv);
        }
      }
  }
}

// ---------------- launcher ----------------
extern "C" void kernel_launch(void* const* d_in, const int* in_sizes, int n_in,
                              void* d_out, int out_size, void* d_ws, size_t ws_size,
                              hipStream_t stream) {
  (void)in_sizes; (void)n_in; (void)out_size; (void)ws_size;
  const float* x  = (const float*)d_in[0];
  const float* Wq = (const float*)d_in[1];
  const float* bq = (const float*)d_in[2];
  const float* Wk = (const float*)d_in[3];
  const float* bk = (const float*)d_in[4];
  const float* Wv = (const float*)d_in[5];
  const float* bv = (const float*)d_in[6];
  const float* Wo = (const float*)d_in[7];
  const float* bo = (const float*)d_in[8];
  float* out = (float*)d_out;

  char* ws = (char*)d_ws;
  short* xb  = (short*)(ws);
  short* Wqt = (short*)(ws + 8388608);
  short* Wkt = Wqt + 1048576;
  short* Wvt = Wkt + 1048576;
  short* Wot = Wvt + 1048576;
  short* Qb  = Wot + 1048576;
  short* Kb  = Qb + 4194304;
  short* Vtb = Kb + 4194304;
  short* Ob  = Vtb + 4194304;

  prep_kernel<<<dim3(32, 32, 8), dim3(32, 8), 0, stream>>>(
      x, Wq, Wk, Wv, Wo, xb, Wqt, Wkt, Wvt, Wot);
  qkv_gemm<<<768, 256, 0, stream>>>(
      xb, Wqt, Wkt, Wvt, bq, bk, bv, Qb, Kb, Vtb);
  attn_kernel<<<512, 256, 0, stream>>>(Qb, Kb, Vtb, Ob);
  out_gemm<<<256, 256, 0, stream>>>(Ob, Wot, bo, out);
}

// Round 10
// 185.015 us; speedup vs baseline: 1.0153x; 1.0153x over previous
//
#include <hip/hip_runtime.h>
#include <hip/hip_bf16.h>

#define B_  2
#define S_  2048
#define D_  1024
#define H_  16
#define HD_ 64

typedef __attribute__((ext_vector_type(8))) short bf16x8;
typedef __attribute__((ext_vector_type(4))) short bf16x4;
typedef __attribute__((ext_vector_type(4))) float f32x4;

typedef __attribute__((address_space(1))) const short gbl_short;
typedef __attribute__((address_space(3))) short lds_short;

__device__ __forceinline__ short f2bf(float f) {
  union { float f; unsigned u; } v; v.f = f;
  unsigned r = (v.u + 0x7FFFu + ((v.u >> 16) & 1u)) >> 16;
  return (short)r;
}

__device__ __forceinline__ short bf16s(float f) {
  __hip_bfloat16 h = __float2bfloat16(f);
  return *reinterpret_cast<short*>(&h);
}

// packed f32x2 -> bf16x2 (RNE), no builtin on gfx950 (T12 recipe)
__device__ __forceinline__ unsigned cvtpk(float lo, float hi) {
  unsigned r;
  asm("v_cvt_pk_bf16_f32 %0, %1, %2" : "=v"(r) : "v"(lo), "v"(hi));
  return r;
}

// ---------------- merged prep: weight transpose+cast (z=0..3) | x cast (z=4..7) ----------------
__global__ __launch_bounds__(256) void prep_kernel(
    const float* __restrict__ x,
    const float* __restrict__ w0, const float* __restrict__ w1,
    const float* __restrict__ w2, const float* __restrict__ w3,
    short* __restrict__ xb,
    short* __restrict__ t0, short* __restrict__ t1,
    short* __restrict__ t2, short* __restrict__ t3) {
  const int z = blockIdx.z;
  if (z < 4) {
    const float* W = z == 0 ? w0 : z == 1 ? w1 : z == 2 ? w2 : w3;
    short* T       = z == 0 ? t0 : z == 1 ? t1 : z == 2 ? t2 : t3;
    __shared__ float tile[32][33];
    int tx = threadIdx.x, ty = threadIdx.y;
    int x0 = blockIdx.x * 32, y0 = blockIdx.y * 32;
#pragma unroll
    for (int i = 0; i < 4; ++i)
      tile[ty + i * 8][tx] = W[(y0 + ty + i * 8) * D_ + x0 + tx];
    __syncthreads();
#pragma unroll
    for (int i = 0; i < 4; ++i)
      T[(x0 + ty + i * 8) * D_ + y0 + tx] = f2bf(tile[tx][ty + i * 8]);
  } else {
    // cast 4M floats as 1M float4 across 4096 virtual blocks (z=4..7 x 32 x 32)
    int bid = (z - 4) * 1024 + blockIdx.y * 32 + blockIdx.x;
    int i = bid * 256 + threadIdx.y * 32 + threadIdx.x;
    float4 v = ((const float4*)x)[i];
    short4 o;
    o.x = f2bf(v.x); o.y = f2bf(v.y); o.z = f2bf(v.z); o.w = f2bf(v.w);
    ((short4*)xb)[i] = o;
  }
}

// ---------------- QKV GEMM: 128x128, BK=32, 3-buffer counted-vmcnt pipeline ----------------
__global__ __launch_bounds__(256) void qkv_gemm(
    const short* __restrict__ xb,
    const short* __restrict__ Wqt, const short* __restrict__ Wkt, const short* __restrict__ Wvt,
    const float* __restrict__ bq, const float* __restrict__ bk, const float* __restrict__ bv,
    short* __restrict__ Qb, short* __restrict__ Kb, short* __restrict__ Vtb) {
  const int which = blockIdx.z;
  const short* Bt   = which == 0 ? Wqt : which == 1 ? Wkt : Wvt;
  const float* bias = which == 0 ? bq  : which == 1 ? bk  : bv;
  const float scl   = which == 0 ? 0.125f * 1.44269504089f : 1.0f;
  const int lane = threadIdx.x & 63, wave = threadIdx.x >> 6;
  const int l15 = lane & 15, quad = lane >> 4;
  const int wm = wave & 1, wn = wave >> 1;
  const int m0 = blockIdx.x * 128, n0 = blockIdx.y * 128;
  const int srow = lane >> 2;
  const int skp  = (((lane & 3) ^ ((srow >> 1) & 3)) * 8);
  const int rsw  = (l15 >> 1) & 3;

  __shared__ short lA[3][128 * 32];
  __shared__ short lB[3][128 * 32];

  f32x4 acc[4][4];
#pragma unroll
  for (int mi = 0; mi < 4; ++mi)
#pragma unroll
    for (int ni = 0; ni < 4; ++ni) { f32x4 z = {0.f, 0.f, 0.f, 0.f}; acc[mi][ni] = z; }

  auto stage = [&](int it, int buf) {
    int kk = it * 32;
#pragma unroll
    for (int j = 0; j < 2; ++j) {
      int c = wave * 2 + j;
      int row = c * 16 + srow;
      __builtin_amdgcn_global_load_lds(
          (gbl_short*)(xb + (m0 + row) * D_ + kk + skp),
          (lds_short*)(&lA[buf][0] + c * 512 + lane * 8), 16, 0, 0);
      __builtin_amdgcn_global_load_lds(
          (gbl_short*)(Bt + (n0 + row) * D_ + kk + skp),
          (lds_short*)(&lB[buf][0] + c * 512 + lane * 8), 16, 0, 0);
    }
  };

  auto compute = [&](int cur) {
    bf16x8 af[4], bf[4];
#pragma unroll
    for (int i = 0; i < 4; ++i) {
      af[i] = *(const bf16x8*)(&lA[cur][0] + (wm * 64 + i * 16 + l15) * 32 + ((quad ^ rsw)) * 8);
      bf[i] = *(const bf16x8*)(&lB[cur][0] + (wn * 64 + i * 16 + l15) * 32 + ((quad ^ rsw)) * 8);
    }
#pragma unroll
    for (int mi = 0; mi < 4; ++mi)
#pragma unroll
      for (int ni = 0; ni < 4; ++ni)
        acc[mi][ni] = __builtin_amdgcn_mfma_f32_16x16x32_bf16(af[mi], bf[ni], acc[mi][ni], 0, 0, 0);
  };

  stage(0, 0);
  stage(1, 1);
  for (int it = 0; it < 30; ++it) {
    stage(it + 2, (it + 2) % 3);
    asm volatile("s_waitcnt vmcnt(8)" ::: "memory");
    __builtin_amdgcn_s_barrier();
    compute(it % 3);
    asm volatile("" ::: "memory");
    __builtin_amdgcn_s_barrier();
  }
  asm volatile("s_waitcnt vmcnt(4)" ::: "memory");
  __builtin_amdgcn_s_barrier();
  compute(0);
  asm volatile("s_waitcnt vmcnt(0)" ::: "memory");
  __builtin_amdgcn_s_barrier();
  compute(1);

#pragma unroll
  for (int mi = 0; mi < 4; ++mi) {
    int m = m0 + wm * 64 + mi * 16 + quad * 4;
    int bb = m >> 11;
    int s0 = m & (S_ - 1);
#pragma unroll
    for (int ni = 0; ni < 4; ++ni) {
      int n = n0 + wn * 64 + ni * 16 + l15;
      int h = n >> 6, hd = n & 63;
      float bsv = bias[n];
      if (which < 2) {
        short* dst = which == 0 ? Qb : Kb;
#pragma unroll
        for (int r = 0; r < 4; ++r)
          dst[((bb * H_ + h) * S_ + (s0 + r)) * HD_ + hd] = f2bf((acc[mi][ni][r] + bsv) * scl);
      } else {
        short4 pk;
        pk.x = f2bf(acc[mi][ni][0] + bsv);
        pk.y = f2bf(acc[mi][ni][1] + bsv);
        pk.z = f2bf(acc[mi][ni][2] + bsv);
        pk.w = f2bf(acc[mi][ni][3] + bsv);
        *(short4*)(Vtb + ((bb * H_ + h) * HD_ + hd) * S_ + s0) = pk;
      }
    }
  }
}

// ---------------- output projection: 128x128, same 3-buffer pipeline ----------------
__global__ __launch_bounds__(256) void out_gemm(
    const short* __restrict__ Ob, const short* __restrict__ Wot,
    const float* __restrict__ bo, float* __restrict__ out) {
  const int lane = threadIdx.x & 63, wave = threadIdx.x >> 6;
  const int l15 = lane & 15, quad = lane >> 4;
  const int wm = wave & 1, wn = wave >> 1;
  const int m0 = blockIdx.x * 128, n0 = blockIdx.y * 128;
  const int srow = lane >> 2;
  const int skp  = (((lane & 3) ^ ((srow >> 1) & 3)) * 8);
  const int rsw  = (l15 >> 1) & 3;

  __shared__ short lA[3][128 * 32];
  __shared__ short lB[3][128 * 32];

  f32x4 acc[4][4];
#pragma unroll
  for (int mi = 0; mi < 4; ++mi)
#pragma unroll
    for (int ni = 0; ni < 4; ++ni) { f32x4 z = {0.f, 0.f, 0.f, 0.f}; acc[mi][ni] = z; }

  auto stage = [&](int it, int buf) {
    int kk = it * 32;
#pragma unroll
    for (int j = 0; j < 2; ++j) {
      int c = wave * 2 + j;
      int row = c * 16 + srow;
      __builtin_amdgcn_global_load_lds(
          (gbl_short*)(Ob + (m0 + row) * D_ + kk + skp),
          (lds_short*)(&lA[buf][0] + c * 512 + lane * 8), 16, 0, 0);
      __builtin_amdgcn_global_load_lds(
          (gbl_short*)(Wot + (n0 + row) * D_ + kk + skp),
          (lds_short*)(&lB[buf][0] + c * 512 + lane * 8), 16, 0, 0);
    }
  };

  auto compute = [&](int cur) {
    bf16x8 af[4], bf[4];
#pragma unroll
    for (int i = 0; i < 4; ++i) {
      af[i] = *(const bf16x8*)(&lA[cur][0] + (wm * 64 + i * 16 + l15) * 32 + ((quad ^ rsw)) * 8);
      bf[i] = *(const bf16x8*)(&lB[cur][0] + (wn * 64 + i * 16 + l15) * 32 + ((quad ^ rsw)) * 8);
    }
#pragma unroll
    for (int mi = 0; mi < 4; ++mi)
#pragma unroll
      for (int ni = 0; ni < 4; ++ni)
        acc[mi][ni] = __builtin_amdgcn_mfma_f32_16x16x32_bf16(af[mi], bf[ni], acc[mi][ni], 0, 0, 0);
  };

  stage(0, 0);
  stage(1, 1);
  for (int it = 0; it < 30; ++it) {
    stage(it + 2, (it + 2) % 3);
    asm volatile("s_waitcnt vmcnt(8)" ::: "memory");
    __builtin_amdgcn_s_barrier();
    compute(it % 3);
    asm volatile("" ::: "memory");
    __builtin_amdgcn_s_barrier();
  }
  asm volatile("s_waitcnt vmcnt(4)" ::: "memory");
  __builtin_amdgcn_s_barrier();
  compute(0);
  asm volatile("s_waitcnt vmcnt(0)" ::: "memory");
  __builtin_amdgcn_s_barrier();
  compute(1);

#pragma unroll
  for (int mi = 0; mi < 4; ++mi) {
    int m = m0 + wm * 64 + mi * 16 + quad * 4;
#pragma unroll
    for (int ni = 0; ni < 4; ++ni) {
      int n = n0 + wn * 64 + ni * 16 + l15;
      float bsv = bo[n];
#pragma unroll
      for (int r = 0; r < 4; ++r)
        out[(m + r) * D_ + n] = acc[mi][ni][r] + bsv;
    }
  }
}

// ---------------- Flash attention v12 (round-6 verified source, session best) ----------------
// 4 LDS buffers, stage 2 tiles -> vmcnt(8) -> barrier -> compute(t),
// compute(t+1) -> barrier.  cvt_pk softmax pack.  XCD pair-swizzle + setprio +
// S^T register-P trick.  v13 (zero-C) and v14 (512-thr 4-way split) both
// failed refcheck with unexplained mechanisms -> dropped per rigor discipline.
__global__ __launch_bounds__(256, 2) void attn_kernel(
    const short* __restrict__ Qb, const short* __restrict__ Kb,
    const short* __restrict__ Vtb, short* __restrict__ Ob) {
  // XCD-aware decode: id = xcd + 8*(s*16 + qt), pair = xcd*4 + s
  const int id = blockIdx.x;
  const int xcd = id & 7;
  const int slot = id >> 3;                        // 0..63
  const int pr = xcd * 4 + (slot >> 4);            // 0..31
  const int qt = slot & 15;
  const int h = pr & 15, b = pr >> 4;
  const int base = (b * H_ + h) * S_ * HD_;
  const int tid = threadIdx.x;
  const int lane = tid & 63, wave = tid >> 6;      // 0..3
  const int grp = wave >> 1;                       // key-half
  const int wq  = wave & 1;                        // q-subtile (64 q)
  const int l15 = lane & 15, quad = lane >> 4;

  __shared__ __align__(16) char smem[65536];
  short* lK = (short*)smem;                        // [4 buf][2 grp][32key*64hd]
  short* lV = (short*)(smem + 32768);              // [4 buf][2 grp][64hd*32key]

  const int q0 = qt * 128 + wq * 64;

  bf16x8 qf[4][2];
#pragma unroll
  for (int mi = 0; mi < 4; ++mi)
#pragma unroll
    for (int ks = 0; ks < 2; ++ks)
      qf[mi][ks] = *(const bf16x8*)(Qb + base + (q0 + mi * 16 + l15) * HD_ + ks * 32 + quad * 8);

  f32x4 oacc[4][4];
  f32x4 lacc[4];
#pragma unroll
  for (int mi = 0; mi < 4; ++mi) {
    f32x4 z = {0.f, 0.f, 0.f, 0.f};
    lacc[mi] = z;
#pragma unroll
    for (int nb = 0; nb < 4; ++nb) oacc[mi][nb] = z;
  }

  bf16x8 onesf;
#pragma unroll
  for (int i = 0; i < 8; ++i) onesf[i] = (short)0x3F80;   // bf16 1.0

  const int tig = tid & 127;
  const int slotK = tig & 7,  rowK = tig >> 3;     // K: 16 rows x 8 slots (+j*16)
  const int slotV = tig & 3,  rowV = tig >> 2;     // V: 32 rows x 4 slots (+j*32)
  const short* kp = Kb + base + (grp * 1024 + rowK) * HD_ + ((slotK ^ (rowK & 7)) * 8);
  const short* vp = Vtb + base + rowV * S_ + grp * 1024 + ((slotV ^ ((rowV >> 2) & 3)) * 8);
  lds_short* ldk = (lds_short*)(lK + grp * 2048 + tig * 8);
  lds_short* ldv = (lds_short*)(lV + grp * 2048 + tig * 8);

  auto stage = [&](int kt, int buf) {
#pragma unroll
    for (int j = 0; j < 2; ++j) {
      __builtin_amdgcn_global_load_lds((gbl_short*)(kp + kt * 32 * HD_ + j * 16 * HD_),
                                       ldk + buf * 4096 + j * 1024, 16, 0, 0);
      __builtin_amdgcn_global_load_lds((gbl_short*)(vp + kt * 32 + j * 32 * S_),
                                       ldv + buf * 4096 + j * 1024, 16, 0, 0);
    }
  };

  const int swzK = l15 & 7;                        // K 16B-group XOR key
  const int fsw  = (l15 >> 2) & 3;                 // V 16B-group XOR key
  const int g1 = (quad >> 1) ^ fsw;                // V physical group, keys quad*4+0..3
  const int g2 = (2 | (quad >> 1)) ^ fsw;          // V physical group, keys 16+quad*4+0..3
  const int vsub = (quad & 1) * 4;                 // 8B half within 16B group

  auto compute = [&](int buf) {
    const short* lKc = lK + buf * 4096 + grp * 2048;
    const short* lVc = lV + buf * 4096 + grp * 2048;

    // S^T = K Q^T : sacc[mi][nb], rows=keys nb*16+quad*4+r, cols=q=mi*16+l15
    f32x4 sacc[4][2];
#pragma unroll
    for (int mi = 0; mi < 4; ++mi)
#pragma unroll
      for (int nb = 0; nb < 2; ++nb) { f32x4 z = {0.f, 0.f, 0.f, 0.f}; sacc[mi][nb] = z; }
    __builtin_amdgcn_s_setprio(1);
#pragma unroll
    for (int nb = 0; nb < 2; ++nb)
#pragma unroll
      for (int ks = 0; ks < 2; ++ks) {
        bf16x8 kf = *(const bf16x8*)(lKc + (nb * 16 + l15) * 64 + (((ks * 4 + quad) ^ swzK) * 8));
#pragma unroll
        for (int mi = 0; mi < 4; ++mi)
          sacc[mi][nb] = __builtin_amdgcn_mfma_f32_16x16x32_bf16(kf, qf[mi][ks], sacc[mi][nb], 0, 0, 0);
      }
    __builtin_amdgcn_s_setprio(0);

    // P A-fragments in registers via exp2 + packed cvt
    bf16x8 af[4];
#pragma unroll
    for (int mi = 0; mi < 4; ++mi) {
      union { bf16x8 v; unsigned u[4]; } aw;
#pragma unroll
      for (int p = 0; p < 4; ++p)
        aw.u[p] = cvtpk(__builtin_amdgcn_exp2f(sacc[mi][p >> 1][(p & 1) * 2]),
                        __builtin_amdgcn_exp2f(sacc[mi][p >> 1][(p & 1) * 2 + 1]));
      af[mi] = aw.v;
    }

    // O += P V (same sigma on V's k): vf = two b64 runs per nbh
    __builtin_amdgcn_s_setprio(1);
#pragma unroll
    for (int nbh = 0; nbh < 4; ++nbh) {
      const short* vrow = lVc + (nbh * 16 + l15) * 32 + vsub;
      bf16x4 v1 = *(const bf16x4*)(vrow + g1 * 8);
      bf16x4 v2 = *(const bf16x4*)(vrow + g2 * 8);
      bf16x8 vf = __builtin_shufflevector(v1, v2, 0, 1, 2, 3, 4, 5, 6, 7);
#pragma unroll
      for (int mi = 0; mi < 4; ++mi)
        oacc[mi][nbh] = __builtin_amdgcn_mfma_f32_16x16x32_bf16(af[mi], vf, oacc[mi][nbh], 0, 0, 0);
    }
#pragma unroll
    for (int mi = 0; mi < 4; ++mi)
      lacc[mi] = __builtin_amdgcn_mfma_f32_16x16x32_bf16(af[mi], onesf, lacc[mi], 0, 0, 0);
    __builtin_amdgcn_s_setprio(0);
  };

  // drain Q-fragment loads so loop vmcnt counting is exact
  asm volatile("s_waitcnt vmcnt(0)" ::: "memory");
  stage(0, 0);
  stage(1, 1);

  for (int t = 0; t < 32; t += 2) {
    if (t < 30) {
      stage(t + 2, (t + 2) & 3);
      stage(t + 3, (t + 3) & 3);
      asm volatile("s_waitcnt vmcnt(8)" ::: "memory");
    } else {
      asm volatile("s_waitcnt vmcnt(0)" ::: "memory");
    }
    __builtin_amdgcn_s_barrier();
    compute(t & 3);
    compute((t + 1) & 3);
    asm volatile("" ::: "memory");
    __builtin_amdgcn_s_barrier();
  }

  // merge the two key-halves through LDS, normalize + write
  float* exch = (float*)smem;                      // 2 wq x 64q x 64hd f32 = 32 KB
  float* lex  = (float*)(smem + 32768);            // 128 floats (lV region, done)
  if (grp == 1) {
#pragma unroll
    for (int mi = 0; mi < 4; ++mi)
#pragma unroll
      for (int nbh = 0; nbh < 4; ++nbh)
#pragma unroll
        for (int r = 0; r < 4; ++r)
          exch[wq * 4096 + (mi * 16 + quad * 4 + r) * 64 + nbh * 16 + l15] = oacc[mi][nbh][r];
    if (l15 == 0) {
#pragma unroll
      for (int mi = 0; mi < 4; ++mi)
#pragma unroll
        for (int r = 0; r < 4; ++r)
          lex[wq * 64 + mi * 16 + quad * 4 + r] = lacc[mi][r];
    }
  }
  __syncthreads();
  if (grp == 0) {
#pragma unroll
    for (int mi = 0; mi < 4; ++mi)
#pragma unroll
      for (int r = 0; r < 4; ++r) {
        int row = mi * 16 + quad * 4 + r;
        float l2 = lex[wq * 64 + row];
        float inv = 1.0f / (lacc[mi][r] + l2);
        int sg = q0 + row;
#pragma unroll
        for (int nbh = 0; nbh < 4; ++nbh) {
          float o2 = exch[wq * 4096 + row * 64 + nbh * 16 + l15];
          Ob[(b * S_ + sg) * D_ + h * HD_ + nbh * 16 + l15] =
              bf16s((oacc[mi][nbh][r] + o2) * inv);
        }
      }
  }
}

// ---------------- launcher ----------------
extern "C" void kernel_launch(void* const* d_in, const int* in_sizes, int n_in,
                              void* d_out, int out_size, void* d_ws, size_t ws_size,
                              hipStream_t stream) {
  (void)in_sizes; (void)n_in; (void)out_size; (void)ws_size;
  const float* x  = (const float*)d_in[0];
  const float* Wq = (const float*)d_in[1];
  const float* bq = (const float*)d_in[2];
  const float* Wk = (const float*)d_in[3];
  const float* bk = (const float*)d_in[4];
  const float* Wv = (const float*)d_in[5];
  const float* bv = (const float*)d_in[6];
  const float* Wo = (const float*)d_in[7];
  const float* bo = (const float*)d_in[8];
  float* out = (float*)d_out;

  char* ws = (char*)d_ws;
  short* xb  = (short*)(ws);
  short* Wqt = (short*)(ws + 8388608);
  short* Wkt = Wqt + 1048576;
  short* Wvt = Wkt + 1048576;
  short* Wot = Wvt + 1048576;
  short* Qb  = Wot + 1048576;
  short* Kb  = Qb + 4194304;
  short* Vtb = Kb + 4194304;
  short* Ob  = Vtb + 4194304;

  prep_kernel<<<dim3(32, 32, 8), dim3(32, 8), 0, stream>>>(
      x, Wq, Wk, Wv, Wo, xb, Wqt, Wkt, Wvt, Wot);
  qkv_gemm<<<dim3(32, 8, 3), 256, 0, stream>>>(
      xb, Wqt, Wkt, Wvt, bq, bk, bv, Qb, Kb, Vtb);
  attn_kernel<<<512, 256, 0, stream>>>(Qb, Kb, Vtb, Ob);
  out_gemm<<<dim3(32, 8), 256, 0, stream>>>(Ob, Wot, bo, out);
}

// Round 12
// 184.583 us; speedup vs baseline: 1.0177x; 1.0023x over previous
//
#include <hip/hip_runtime.h>
#include <hip/hip_bf16.h>

#define B_  2
#define S_  2048
#define D_  1024
#define H_  16
#define HD_ 64

typedef __attribute__((ext_vector_type(8))) short bf16x8;
typedef __attribute__((ext_vector_type(4))) short bf16x4;
typedef __attribute__((ext_vector_type(4))) float f32x4;

typedef __attribute__((address_space(1))) const short gbl_short;
typedef __attribute__((address_space(3))) short lds_short;

__device__ __forceinline__ short f2bf(float f) {
  union { float f; unsigned u; } v; v.f = f;
  unsigned r = (v.u + 0x7FFFu + ((v.u >> 16) & 1u)) >> 16;
  return (short)r;
}

__device__ __forceinline__ short bf16s(float f) {
  __hip_bfloat16 h = __float2bfloat16(f);
  return *reinterpret_cast<short*>(&h);
}

// packed f32x2 -> bf16x2 (RNE), no builtin on gfx950 (T12 recipe)
__device__ __forceinline__ unsigned cvtpk(float lo, float hi) {
  unsigned r;
  asm("v_cvt_pk_bf16_f32 %0, %1, %2" : "=v"(r) : "v"(lo), "v"(hi));
  return r;
}

// ---------------- merged prep: weight transpose+cast (z=0..3) | x cast (z=4..7) ----------------
__global__ __launch_bounds__(256) void prep_kernel(
    const float* __restrict__ x,
    const float* __restrict__ w0, const float* __restrict__ w1,
    const float* __restrict__ w2, const float* __restrict__ w3,
    short* __restrict__ xb,
    short* __restrict__ t0, short* __restrict__ t1,
    short* __restrict__ t2, short* __restrict__ t3) {
  const int z = blockIdx.z;
  if (z < 4) {
    const float* W = z == 0 ? w0 : z == 1 ? w1 : z == 2 ? w2 : w3;
    short* T       = z == 0 ? t0 : z == 1 ? t1 : z == 2 ? t2 : t3;
    __shared__ float tile[32][33];
    int tx = threadIdx.x, ty = threadIdx.y;
    int x0 = blockIdx.x * 32, y0 = blockIdx.y * 32;
#pragma unroll
    for (int i = 0; i < 4; ++i)
      tile[ty + i * 8][tx] = W[(y0 + ty + i * 8) * D_ + x0 + tx];
    __syncthreads();
#pragma unroll
    for (int i = 0; i < 4; ++i)
      T[(x0 + ty + i * 8) * D_ + y0 + tx] = f2bf(tile[tx][ty + i * 8]);
  } else {
    // cast 4M floats as 1M float4 across 4096 virtual blocks (z=4..7 x 32 x 32)
    int bid = (z - 4) * 1024 + blockIdx.y * 32 + blockIdx.x;
    int i = bid * 256 + threadIdx.y * 32 + threadIdx.x;
    float4 v = ((const float4*)x)[i];
    short4 o;
    o.x = f2bf(v.x); o.y = f2bf(v.y); o.z = f2bf(v.z); o.w = f2bf(v.w);
    ((short4*)xb)[i] = o;
  }
}

// ---------------- QKV GEMM: 128x128, BK=32, 3-buffer counted-vmcnt pipeline ----------------
__global__ __launch_bounds__(256) void qkv_gemm(
    const short* __restrict__ xb,
    const short* __restrict__ Wqt, const short* __restrict__ Wkt, const short* __restrict__ Wvt,
    const float* __restrict__ bq, const float* __restrict__ bk, const float* __restrict__ bv,
    short* __restrict__ Qb, short* __restrict__ Kb, short* __restrict__ Vtb) {
  const int which = blockIdx.z;
  const short* Bt   = which == 0 ? Wqt : which == 1 ? Wkt : Wvt;
  const float* bias = which == 0 ? bq  : which == 1 ? bk  : bv;
  const float scl   = which == 0 ? 0.125f * 1.44269504089f : 1.0f;
  const int lane = threadIdx.x & 63, wave = threadIdx.x >> 6;
  const int l15 = lane & 15, quad = lane >> 4;
  const int wm = wave & 1, wn = wave >> 1;
  const int m0 = blockIdx.x * 128, n0 = blockIdx.y * 128;
  const int srow = lane >> 2;
  const int skp  = (((lane & 3) ^ ((srow >> 1) & 3)) * 8);
  const int rsw  = (l15 >> 1) & 3;

  __shared__ short lA[3][128 * 32];
  __shared__ short lB[3][128 * 32];

  f32x4 acc[4][4];
#pragma unroll
  for (int mi = 0; mi < 4; ++mi)
#pragma unroll
    for (int ni = 0; ni < 4; ++ni) { f32x4 z = {0.f, 0.f, 0.f, 0.f}; acc[mi][ni] = z; }

  auto stage = [&](int it, int buf) {
    int kk = it * 32;
#pragma unroll
    for (int j = 0; j < 2; ++j) {
      int c = wave * 2 + j;
      int row = c * 16 + srow;
      __builtin_amdgcn_global_load_lds(
          (gbl_short*)(xb + (m0 + row) * D_ + kk + skp),
          (lds_short*)(&lA[buf][0] + c * 512 + lane * 8), 16, 0, 0);
      __builtin_amdgcn_global_load_lds(
          (gbl_short*)(Bt + (n0 + row) * D_ + kk + skp),
          (lds_short*)(&lB[buf][0] + c * 512 + lane * 8), 16, 0, 0);
    }
  };

  auto compute = [&](int cur) {
    bf16x8 af[4], bf[4];
#pragma unroll
    for (int i = 0; i < 4; ++i) {
      af[i] = *(const bf16x8*)(&lA[cur][0] + (wm * 64 + i * 16 + l15) * 32 + ((quad ^ rsw)) * 8);
      bf[i] = *(const bf16x8*)(&lB[cur][0] + (wn * 64 + i * 16 + l15) * 32 + ((quad ^ rsw)) * 8);
    }
#pragma unroll
    for (int mi = 0; mi < 4; ++mi)
#pragma unroll
      for (int ni = 0; ni < 4; ++ni)
        acc[mi][ni] = __builtin_amdgcn_mfma_f32_16x16x32_bf16(af[mi], bf[ni], acc[mi][ni], 0, 0, 0);
  };

  stage(0, 0);
  stage(1, 1);
  for (int it = 0; it < 30; ++it) {
    stage(it + 2, (it + 2) % 3);
    asm volatile("s_waitcnt vmcnt(8)" ::: "memory");
    __builtin_amdgcn_s_barrier();
    compute(it % 3);
    asm volatile("" ::: "memory");
    __builtin_amdgcn_s_barrier();
  }
  asm volatile("s_waitcnt vmcnt(4)" ::: "memory");
  __builtin_amdgcn_s_barrier();
  compute(0);
  asm volatile("s_waitcnt vmcnt(0)" ::: "memory");
  __builtin_amdgcn_s_barrier();
  compute(1);

#pragma unroll
  for (int mi = 0; mi < 4; ++mi) {
    int m = m0 + wm * 64 + mi * 16 + quad * 4;
    int bb = m >> 11;
    int s0 = m & (S_ - 1);
#pragma unroll
    for (int ni = 0; ni < 4; ++ni) {
      int n = n0 + wn * 64 + ni * 16 + l15;
      int h = n >> 6, hd = n & 63;
      float bsv = bias[n];
      if (which < 2) {
        short* dst = which == 0 ? Qb : Kb;
#pragma unroll
        for (int r = 0; r < 4; ++r)
          dst[((bb * H_ + h) * S_ + (s0 + r)) * HD_ + hd] = f2bf((acc[mi][ni][r] + bsv) * scl);
      } else {
        short4 pk;
        pk.x = f2bf(acc[mi][ni][0] + bsv);
        pk.y = f2bf(acc[mi][ni][1] + bsv);
        pk.z = f2bf(acc[mi][ni][2] + bsv);
        pk.w = f2bf(acc[mi][ni][3] + bsv);
        *(short4*)(Vtb + ((bb * H_ + h) * HD_ + hd) * S_ + s0) = pk;
      }
    }
  }
}

// ---------------- output projection: 128x128, same 3-buffer pipeline ----------------
__global__ __launch_bounds__(256) void out_gemm(
    const short* __restrict__ Ob, const short* __restrict__ Wot,
    const float* __restrict__ bo, float* __restrict__ out) {
  const int lane = threadIdx.x & 63, wave = threadIdx.x >> 6;
  const int l15 = lane & 15, quad = lane >> 4;
  const int wm = wave & 1, wn = wave >> 1;
  const int m0 = blockIdx.x * 128, n0 = blockIdx.y * 128;
  const int srow = lane >> 2;
  const int skp  = (((lane & 3) ^ ((srow >> 1) & 3)) * 8);
  const int rsw  = (l15 >> 1) & 3;

  __shared__ short lA[3][128 * 32];
  __shared__ short lB[3][128 * 32];

  f32x4 acc[4][4];
#pragma unroll
  for (int mi = 0; mi < 4; ++mi)
#pragma unroll
    for (int ni = 0; ni < 4; ++ni) { f32x4 z = {0.f, 0.f, 0.f, 0.f}; acc[mi][ni] = z; }

  auto stage = [&](int it, int buf) {
    int kk = it * 32;
#pragma unroll
    for (int j = 0; j < 2; ++j) {
      int c = wave * 2 + j;
      int row = c * 16 + srow;
      __builtin_amdgcn_global_load_lds(
          (gbl_short*)(Ob + (m0 + row) * D_ + kk + skp),
          (lds_short*)(&lA[buf][0] + c * 512 + lane * 8), 16, 0, 0);
      __builtin_amdgcn_global_load_lds(
          (gbl_short*)(Wot + (n0 + row) * D_ + kk + skp),
          (lds_short*)(&lB[buf][0] + c * 512 + lane * 8), 16, 0, 0);
    }
  };

  auto compute = [&](int cur) {
    bf16x8 af[4], bf[4];
#pragma unroll
    for (int i = 0; i < 4; ++i) {
      af[i] = *(const bf16x8*)(&lA[cur][0] + (wm * 64 + i * 16 + l15) * 32 + ((quad ^ rsw)) * 8);
      bf[i] = *(const bf16x8*)(&lB[cur][0] + (wn * 64 + i * 16 + l15) * 32 + ((quad ^ rsw)) * 8);
    }
#pragma unroll
    for (int mi = 0; mi < 4; ++mi)
#pragma unroll
      for (int ni = 0; ni < 4; ++ni)
        acc[mi][ni] = __builtin_amdgcn_mfma_f32_16x16x32_bf16(af[mi], bf[ni], acc[mi][ni], 0, 0, 0);
  };

  stage(0, 0);
  stage(1, 1);
  for (int it = 0; it < 30; ++it) {
    stage(it + 2, (it + 2) % 3);
    asm volatile("s_waitcnt vmcnt(8)" ::: "memory");
    __builtin_amdgcn_s_barrier();
    compute(it % 3);
    asm volatile("" ::: "memory");
    __builtin_amdgcn_s_barrier();
  }
  asm volatile("s_waitcnt vmcnt(4)" ::: "memory");
  __builtin_amdgcn_s_barrier();
  compute(0);
  asm volatile("s_waitcnt vmcnt(0)" ::: "memory");
  __builtin_amdgcn_s_barrier();
  compute(1);

#pragma unroll
  for (int mi = 0; mi < 4; ++mi) {
    int m = m0 + wm * 64 + mi * 16 + quad * 4;
#pragma unroll
    for (int ni = 0; ni < 4; ++ni) {
      int n = n0 + wn * 64 + ni * 16 + l15;
      float bsv = bo[n];
#pragma unroll
      for (int r = 0; r < 4; ++r)
        out[(m + r) * D_ + n] = acc[mi][ni][r] + bsv;
    }
  }
}

// ---------------- Flash attention v12 (round-6/10 verified source, session best) ----------------
// 4 LDS buffers, stage 2 tiles -> vmcnt(8) -> barrier -> compute(t),
// compute(t+1) -> barrier.  cvt_pk softmax pack.  XCD pair-swizzle + setprio +
// S^T register-P trick.  v13 (zero-C), v14 (512-thr split), R11 (Q/K store
// transpose) all failed refcheck with mechanisms static analysis could not
// resolve -> dropped per rigor discipline.
__global__ __launch_bounds__(256, 2) void attn_kernel(
    const short* __restrict__ Qb, const short* __restrict__ Kb,
    const short* __restrict__ Vtb, short* __restrict__ Ob) {
  // XCD-aware decode: id = xcd + 8*(s*16 + qt), pair = xcd*4 + s
  const int id = blockIdx.x;
  const int xcd = id & 7;
  const int slot = id >> 3;                        // 0..63
  const int pr = xcd * 4 + (slot >> 4);            // 0..31
  const int qt = slot & 15;
  const int h = pr & 15, b = pr >> 4;
  const int base = (b * H_ + h) * S_ * HD_;
  const int tid = threadIdx.x;
  const int lane = tid & 63, wave = tid >> 6;      // 0..3
  const int grp = wave >> 1;                       // key-half
  const int wq  = wave & 1;                        // q-subtile (64 q)
  const int l15 = lane & 15, quad = lane >> 4;

  __shared__ __align__(16) char smem[65536];
  short* lK = (short*)smem;                        // [4 buf][2 grp][32key*64hd]
  short* lV = (short*)(smem + 32768);              // [4 buf][2 grp][64hd*32key]

  const int q0 = qt * 128 + wq * 64;

  bf16x8 qf[4][2];
#pragma unroll
  for (int mi = 0; mi < 4; ++mi)
#pragma unroll
    for (int ks = 0; ks < 2; ++ks)
      qf[mi][ks] = *(const bf16x8*)(Qb + base + (q0 + mi * 16 + l15) * HD_ + ks * 32 + quad * 8);

  f32x4 oacc[4][4];
  f32x4 lacc[4];
#pragma unroll
  for (int mi = 0; mi < 4; ++mi) {
    f32x4 z = {0.f, 0.f, 0.f, 0.f};
    lacc[mi] = z;
#pragma unroll
    for (int nb = 0; nb < 4; ++nb) oacc[mi][nb] = z;
  }

  bf16x8 onesf;
#pragma unroll
  for (int i = 0; i < 8; ++i) onesf[i] = (short)0x3F80;   // bf16 1.0

  const int tig = tid & 127;
  const int slotK = tig & 7,  rowK = tig >> 3;     // K: 16 rows x 8 slots (+j*16)
  const int slotV = tig & 3,  rowV = tig >> 2;     // V: 32 rows x 4 slots (+j*32)
  const short* kp = Kb + base + (grp * 1024 + rowK) * HD_ + ((slotK ^ (rowK & 7)) * 8);
  const short* vp = Vtb + base + rowV * S_ + grp * 1024 + ((slotV ^ ((rowV >> 2) & 3)) * 8);
  lds_short* ldk = (lds_short*)(lK + grp * 2048 + tig * 8);
  lds_short* ldv = (lds_short*)(lV + grp * 2048 + tig * 8);

  auto stage = [&](int kt, int buf) {
#pragma unroll
    for (int j = 0; j < 2; ++j) {
      __builtin_amdgcn_global_load_lds((gbl_short*)(kp + kt * 32 * HD_ + j * 16 * HD_),
                                       ldk + buf * 4096 + j * 1024, 16, 0, 0);
      __builtin_amdgcn_global_load_lds((gbl_short*)(vp + kt * 32 + j * 32 * S_),
                                       ldv + buf * 4096 + j * 1024, 16, 0, 0);
    }
  };

  const int swzK = l15 & 7;                        // K 16B-group XOR key
  const int fsw  = (l15 >> 2) & 3;                 // V 16B-group XOR key
  const int g1 = (quad >> 1) ^ fsw;                // V physical group, keys quad*4+0..3
  const int g2 = (2 | (quad >> 1)) ^ fsw;          // V physical group, keys 16+quad*4+0..3
  const int vsub = (quad & 1) * 4;                 // 8B half within 16B group

  auto compute = [&](int buf) {
    const short* lKc = lK + buf * 4096 + grp * 2048;
    const short* lVc = lV + buf * 4096 + grp * 2048;

    // S^T = K Q^T : sacc[mi][nb], rows=keys nb*16+quad*4+r, cols=q=mi*16+l15
    f32x4 sacc[4][2];
#pragma unroll
    for (int mi = 0; mi < 4; ++mi)
#pragma unroll
      for (int nb = 0; nb < 2; ++nb) { f32x4 z = {0.f, 0.f, 0.f, 0.f}; sacc[mi][nb] = z; }
    __builtin_amdgcn_s_setprio(1);
#pragma unroll
    for (int nb = 0; nb < 2; ++nb)
#pragma unroll
      for (int ks = 0; ks < 2; ++ks) {
        bf16x8 kf = *(const bf16x8*)(lKc + (nb * 16 + l15) * 64 + (((ks * 4 + quad) ^ swzK) * 8));
#pragma unroll
        for (int mi = 0; mi < 4; ++mi)
          sacc[mi][nb] = __builtin_amdgcn_mfma_f32_16x16x32_bf16(kf, qf[mi][ks], sacc[mi][nb], 0, 0, 0);
      }
    __builtin_amdgcn_s_setprio(0);

    // P A-fragments in registers via exp2 + packed cvt
    bf16x8 af[4];
#pragma unroll
    for (int mi = 0; mi < 4; ++mi) {
      union { bf16x8 v; unsigned u[4]; } aw;
#pragma unroll
      for (int p = 0; p < 4; ++p)
        aw.u[p] = cvtpk(__builtin_amdgcn_exp2f(sacc[mi][p >> 1][(p & 1) * 2]),
                        __builtin_amdgcn_exp2f(sacc[mi][p >> 1][(p & 1) * 2 + 1]));
      af[mi] = aw.v;
    }

    // O += P V (same sigma on V's k): vf = two b64 runs per nbh
    __builtin_amdgcn_s_setprio(1);
#pragma unroll
    for (int nbh = 0; nbh < 4; ++nbh) {
      const short* vrow = lVc + (nbh * 16 + l15) * 32 + vsub;
      bf16x4 v1 = *(const bf16x4*)(vrow + g1 * 8);
      bf16x4 v2 = *(const bf16x4*)(vrow + g2 * 8);
      bf16x8 vf = __builtin_shufflevector(v1, v2, 0, 1, 2, 3, 4, 5, 6, 7);
#pragma unroll
      for (int mi = 0; mi < 4; ++mi)
        oacc[mi][nbh] = __builtin_amdgcn_mfma_f32_16x16x32_bf16(af[mi], vf, oacc[mi][nbh], 0, 0, 0);
    }
#pragma unroll
    for (int mi = 0; mi < 4; ++mi)
      lacc[mi] = __builtin_amdgcn_mfma_f32_16x16x32_bf16(af[mi], onesf, lacc[mi], 0, 0, 0);
    __builtin_amdgcn_s_setprio(0);
  };

  // drain Q-fragment loads so loop vmcnt counting is exact
  asm volatile("s_waitcnt vmcnt(0)" ::: "memory");
  stage(0, 0);
  stage(1, 1);

  for (int t = 0; t < 32; t += 2) {
    if (t < 30) {
      stage(t + 2, (t + 2) & 3);
      stage(t + 3, (t + 3) & 3);
      asm volatile("s_waitcnt vmcnt(8)" ::: "memory");
    } else {
      asm volatile("s_waitcnt vmcnt(0)" ::: "memory");
    }
    __builtin_amdgcn_s_barrier();
    compute(t & 3);
    compute((t + 1) & 3);
    asm volatile("" ::: "memory");
    __builtin_amdgcn_s_barrier();
  }

  // merge the two key-halves through LDS, normalize + write
  float* exch = (float*)smem;                      // 2 wq x 64q x 64hd f32 = 32 KB
  float* lex  = (float*)(smem + 32768);            // 128 floats (lV region, done)
  if (grp == 1) {
#pragma unroll
    for (int mi = 0; mi < 4; ++mi)
#pragma unroll
      for (int nbh = 0; nbh < 4; ++nbh)
#pragma unroll
        for (int r = 0; r < 4; ++r)
          exch[wq * 4096 + (mi * 16 + quad * 4 + r) * 64 + nbh * 16 + l15] = oacc[mi][nbh][r];
    if (l15 == 0) {
#pragma unroll
      for (int mi = 0; mi < 4; ++mi)
#pragma unroll
        for (int r = 0; r < 4; ++r)
          lex[wq * 64 + mi * 16 + quad * 4 + r] = lacc[mi][r];
    }
  }
  __syncthreads();
  if (grp == 0) {
#pragma unroll
    for (int mi = 0; mi < 4; ++mi)
#pragma unroll
      for (int r = 0; r < 4; ++r) {
        int row = mi * 16 + quad * 4 + r;
        float l2 = lex[wq * 64 + row];
        float inv = 1.0f / (lacc[mi][r] + l2);
        int sg = q0 + row;
#pragma unroll
        for (int nbh = 0; nbh < 4; ++nbh) {
          float o2 = exch[wq * 4096 + row * 64 + nbh * 16 + l15];
          Ob[(b * S_ + sg) * D_ + h * HD_ + nbh * 16 + l15] =
              bf16s((oacc[mi][nbh][r] + o2) * inv);
        }
      }
  }
}

// ---------------- launcher ----------------
extern "C" void kernel_launch(void* const* d_in, const int* in_sizes, int n_in,
                              void* d_out, int out_size, void* d_ws, size_t ws_size,
                              hipStream_t stream) {
  (void)in_sizes; (void)n_in; (void)out_size; (void)ws_size;
  const float* x  = (const float*)d_in[0];
  const float* Wq = (const float*)d_in[1];
  const float* bq = (const float*)d_in[2];
  const float* Wk = (const float*)d_in[3];
  const float* bk = (const float*)d_in[4];
  const float* Wv = (const float*)d_in[5];
  const float* bv = (const float*)d_in[6];
  const float* Wo = (const float*)d_in[7];
  const float* bo = (const float*)d_in[8];
  float* out = (float*)d_out;

  char* ws = (char*)d_ws;
  short* xb  = (short*)(ws);
  short* Wqt = (short*)(ws + 8388608);
  short* Wkt = Wqt + 1048576;
  short* Wvt = Wkt + 1048576;
  short* Wot = Wvt + 1048576;
  short* Qb  = Wot + 1048576;
  short* Kb  = Qb + 4194304;
  short* Vtb = Kb + 4194304;
  short* Ob  = Vtb + 4194304;

  prep_kernel<<<dim3(32, 32, 8), dim3(32, 8), 0, stream>>>(
      x, Wq, Wk, Wv, Wo, xb, Wqt, Wkt, Wvt, Wot);
  qkv_gemm<<<dim3(32, 8, 3), 256, 0, stream>>>(
      xb, Wqt, Wkt, Wvt, bq, bk, bv, Qb, Kb, Vtb);
  attn_kernel<<<512, 256, 0, stream>>>(Qb, Kb, Vtb, Ob);
  out_gemm<<<dim3(32, 8), 256, 0, stream>>>(Ob, Wot, bo, out);
}